// Round 3
// baseline (5420.948 us; speedup 1.0000x reference)
//
#include <hip/hip_runtime.h>

#define N_NODES 100000
#define N_EDGES 1600000
#define NBUCK 250          // buckets per (layer,rel)
#define BSZ 400            // nodes per bucket (250*400 = 100000)
#define SUB 50             // dsts per sub-bucket (8 per bucket)
#define NSUB 8
#define CHUNK 8192         // edges per partition block
#define NCHUNK 196         // ceil(E/CHUNK)
#define CAP 8192           // LDS staging capacity in k_bsort
#define MTILES 6250        // N_NODES / 16
#define NTILE 13           // src tiles of 8192 rows (100000 >> 13 -> 0..12)
#define NKEY (BSZ * NTILE) // 5200 sort bins (tile-major: key = tile*BSZ + dd)
#define NKEYP 5376         // padded to 21*256
#define TBL 105            // per-(lr,bucket) range table: 13*8 starts + end

typedef _Float16 half8 __attribute__((ext_vector_type(8)));
typedef _Float16 half2v __attribute__((ext_vector_type(2)));
typedef float floatx4 __attribute__((ext_vector_type(4)));

// workspace layout (bytes), total ~191.4 MB:
#define OFF_DEG   0ull           // 12N int: per layer, out r0..2 then in r0..2
#define OFF_GC    4800000ull     // 1500 int (pad 6144) dst-bucket counts
#define OFF_BB    4806144ull     // dst bucket bases
#define OFF_BC    4812288ull     // dst bucket cursors
#define OFF_RS    4818432ull     // 12N float
#define OFF_START 9618432ull     // tstart tables: 6*250*105 int = 630 KB (in old start buf)
#define OFF_PAIRS 12018432ull    // 6E int
#define OFF_XH    50418432ull    // N*128 fp16 (row-major)
#define OFF_W1F   76018432ull    // 96*512 fp16 (frag order)
#define OFF_W2F   76116736ull    // 48*512 fp16 (frag order)
#define OFF_AGG   76165888ull    // N*384 fp16, A-frag layout; head reused as scratch
#define OFF_HW    152965888ull   // 3 planes of N*64 fp16 (per-relation, pre-scaled)

// scratch aliased into agg region (dead until k_pull1):
#define OFF_DDS   OFF_AGG                    // 6E short = 19.2 MB
#define OFF_GCS   (OFF_AGG + 19200000ull)    // 1500 int (pad 6144)
#define OFF_BBS   (OFF_AGG + 19206144ull)    // 1500 int
#define OFF_BCS   (OFF_AGG + 19212288ull)    // 1500 int
#define OFF_CHD   (OFF_AGG + 19218432ull)    // per-chunk dst hists: 6*196*256 int
#define OFF_CHS   (OFF_AGG + 20422656ull)    // per-chunk src hists

__device__ __forceinline__ void lds_scan256(int* a) {
    int t = threadIdx.x;
    for (int off = 1; off < 256; off <<= 1) {
        int v = (t >= off) ? a[t - off] : 0;
        __syncthreads();
        a[t] += v;
        __syncthreads();
    }
}

// ---------------- fused bucket histograms of src AND dst (+ per-chunk saves) -------------
__global__ __launch_bounds__(256) void k_bhist2(const int* __restrict__ ei,
                                                int* __restrict__ gcount_d,
                                                int* __restrict__ gcount_s,
                                                int* __restrict__ chd,
                                                int* __restrict__ chs) {
    int lr = blockIdx.y;
    int cx = blockIdx.x;
    int e0 = cx * CHUNK;
    int n = min(CHUNK, N_EDGES - e0);
    const int* bs = ei + (size_t)lr * 2 * N_EDGES + e0;
    const int* bd = bs + N_EDGES;
    __shared__ int lhs[256];
    __shared__ int lhd[256];
    int t = threadIdx.x;
    lhs[t] = 0; lhd[t] = 0;
    __syncthreads();
    for (int i = t; i < n; i += 256) {
        atomicAdd(&lhs[bs[i] / BSZ], 1);
        atomicAdd(&lhd[bd[i] / BSZ], 1);
    }
    __syncthreads();
    chd[(lr * NCHUNK + cx) * 256 + t] = lhd[t];
    chs[(lr * NCHUNK + cx) * 256 + t] = lhs[t];
    if (t < NBUCK) {
        if (lhd[t]) atomicAdd(&gcount_d[lr * NBUCK + t], lhd[t]);
        if (lhs[t]) atomicAdd(&gcount_s[lr * NBUCK + t], lhs[t]);
    }
}

// ---------------- scan bucket counts (dst q 0..5, src q 6..11) ----------------
__global__ __launch_bounds__(256) void k_bscan2(const int* __restrict__ gc_d,
                                                const int* __restrict__ gc_s,
                                                int* __restrict__ bb_d,
                                                int* __restrict__ bc_d,
                                                int* __restrict__ bb_s,
                                                int* __restrict__ bc_s) {
    int q = blockIdx.x, t = threadIdx.x;
    int lr = (q < 6) ? q : q - 6;
    const int* gc = (q < 6) ? gc_d : gc_s;
    int* bb = (q < 6) ? bb_d : bb_s;
    int* bc = (q < 6) ? bc_d : bc_s;
    __shared__ int a[256];
    int v = (t < NBUCK) ? gc[lr * NBUCK + t] : 0;
    a[t] = v;
    __syncthreads();
    lds_scan256(a);
    if (t < NBUCK) {
        int excl = a[t] - v;
        bb[lr * NBUCK + t] = excl;
        bc[lr * NBUCK + t] = excl;
    }
}

// ---------------- partition edges into dst buckets (payload src|dd<<17) ----------------
__global__ __launch_bounds__(256) void k_bpart(const int* __restrict__ ei,
                                               const int* __restrict__ chd,
                                               int* __restrict__ bcursor,
                                               int* __restrict__ pairs) {
    int lr = blockIdx.y;
    int cx = blockIdx.x;
    int e0 = cx * CHUNK;
    int n = min(CHUNK, N_EDGES - e0);
    const int* bs = ei + (size_t)lr * 2 * N_EDGES + e0;
    const int* bd = bs + N_EDGES;
    __shared__ int lh[256];
    __shared__ int lexcl[256];
    __shared__ int lcur[256];
    __shared__ int gb[256];
    __shared__ int staged[CHUNK];
    __shared__ unsigned char stb[CHUNK];
    int t = threadIdx.x;
    int cnt_t = chd[(lr * NCHUNK + cx) * 256 + t];
    lh[t] = cnt_t;
    __syncthreads();
    lds_scan256(lh);
    int excl_t = lh[t] - cnt_t;
    lexcl[t] = excl_t;
    lcur[t] = excl_t;
    if (t < NBUCK) gb[t] = cnt_t ? atomicAdd(&bcursor[lr * NBUCK + t], cnt_t) : 0;
    __syncthreads();
    for (int i = t; i < n; i += 256) {
        int s = bs[i], d = bd[i];
        int b = d / BSZ;
        int dd = d - b * BSZ;
        int p = atomicAdd(&lcur[b], 1);
        staged[p] = s | (dd << 17);
        stb[p] = (unsigned char)b;
    }
    __syncthreads();
    int* outp = pairs + (size_t)lr * N_EDGES;
    for (int i = t; i < n; i += 256) {
        int b = stb[i];
        outp[gb[b] + (i - lexcl[b])] = staged[i];
    }
}

// ---------------- partition src into buckets (payload = in-bucket offset) ----------------
__global__ __launch_bounds__(256) void k_bpart_s(const int* __restrict__ ei,
                                                 const int* __restrict__ chs,
                                                 int* __restrict__ bcursor_s,
                                                 short* __restrict__ dds) {
    int lr = blockIdx.y;
    int cx = blockIdx.x;
    int e0 = cx * CHUNK;
    int n = min(CHUNK, N_EDGES - e0);
    const int* bs = ei + (size_t)lr * 2 * N_EDGES + e0;
    __shared__ int lh[256];
    __shared__ int lexcl[256];
    __shared__ int lcur[256];
    __shared__ int gb[256];
    __shared__ short staged[CHUNK];
    __shared__ unsigned char stb[CHUNK];
    int t = threadIdx.x;
    int cnt_t = chs[(lr * NCHUNK + cx) * 256 + t];
    lh[t] = cnt_t;
    __syncthreads();
    lds_scan256(lh);
    int excl_t = lh[t] - cnt_t;
    lexcl[t] = excl_t;
    lcur[t] = excl_t;
    if (t < NBUCK) gb[t] = cnt_t ? atomicAdd(&bcursor_s[lr * NBUCK + t], cnt_t) : 0;
    __syncthreads();
    for (int i = t; i < n; i += 256) {
        int s = bs[i];
        int b = s / BSZ;
        int p = atomicAdd(&lcur[b], 1);
        staged[p] = (short)(s - b * BSZ);
        stb[p] = (unsigned char)b;
    }
    __syncthreads();
    short* outp = dds + (size_t)lr * N_EDGES;
    for (int i = t; i < n; i += 256) {
        int b = stb[i];
        outp[gb[b] + (i - lexcl[b])] = staged[i];
    }
}

// ---------------- per-bucket src count -> out-degree ----------------
__global__ __launch_bounds__(256) void k_bcount_s(const int* __restrict__ bbase_s,
                                                  const short* __restrict__ dds,
                                                  int* __restrict__ deg) {
    int lr = blockIdx.y, b = blockIdx.x;
    int layer = lr / 3, r = lr % 3;
    int base = bbase_s[lr * NBUCK + b];
    int next = (b < NBUCK - 1) ? bbase_s[lr * NBUCK + b + 1] : N_EDGES;
    int cnt = next - base;
    const short* reg = dds + (size_t)lr * N_EDGES + base;
    __shared__ int h[BSZ];
    int t = threadIdx.x;
    h[t] = 0;
    if (t < BSZ - 256) h[t + 256] = 0;
    __syncthreads();
    for (int i = t; i < cnt; i += 256)
        atomicAdd(&h[reg[i]], 1);
    __syncthreads();
    int* degout = deg + (size_t)layer * 6 * N_NODES + (size_t)r * N_NODES + b * BSZ;
    degout[t] = h[t];
    if (t < BSZ - 256) degout[t + 256] = h[t + 256];
}

// -------- per-bucket counting sort by (src-tile, dd) + range table + in-degree ----------
// key = tile*BSZ + dd  (tile-major!). Payload kept full (src | dd<<17).
// tstart[(lr*NBUCK+b)*TBL + t*8 + s] = abs start of (tile t, sub-bucket s); [104] = end.
__global__ __launch_bounds__(256) void k_bsort(const int* __restrict__ bbase,
                                               int* __restrict__ pairs,
                                               int* __restrict__ tstart,
                                               int* __restrict__ deg) {
    int lr = blockIdx.y, b = blockIdx.x;
    int layer = lr / 3, r = lr % 3;
    int base = bbase[lr * NBUCK + b];
    int next = (b < NBUCK - 1) ? bbase[lr * NBUCK + b + 1] : N_EDGES;
    int cnt = next - base;
    int* reg = pairs + (size_t)lr * N_EDGES + base;
    __shared__ int staged[CAP];      // 32 KB
    __shared__ int hist[NKEYP];      // 21.5 KB
    __shared__ int tsum[256];
    int t = threadIdx.x;
    for (int i = t; i < NKEYP; i += 256) hist[i] = 0;
    __syncthreads();
    for (int i = t; i < cnt; i += 256) {
        int v = reg[i];
        if (i < CAP) staged[i] = v;
        int key = ((v & 0x1FFFF) >> 13) * BSZ + (v >> 17);
        atomicAdd(&hist[key], 1);
    }
    __syncthreads();
    // in-degree from raw counts (hist still = counts here)
    {
        int* degout = deg + (size_t)layer * 6 * N_NODES + (size_t)(3 + r) * N_NODES + b * BSZ;
        for (int dd = t; dd < BSZ; dd += 256) {
            int sdeg = 0;
#pragma unroll
            for (int tt = 0; tt < NTILE; tt++) sdeg += hist[tt * BSZ + dd];
            degout[dd] = sdeg;
        }
    }
    // scan 5376 bins: thread t owns bins [t*21, t*21+21)
    int b0 = t * 21;
    int loc[21];
    int s = 0;
#pragma unroll
    for (int k = 0; k < 21; k++) { loc[k] = s; s += hist[b0 + k]; }
    tsum[t] = s;
    __syncthreads();
    lds_scan256(tsum);               // inclusive (internal barriers order deg reads before writes)
    int tbase = tsum[t] - s;
#pragma unroll
    for (int k = 0; k < 21; k++) hist[b0 + k] = tbase + loc[k];
    __syncthreads();
    // range table for tile-phased pulls
    {
        int* tb = tstart + (size_t)(lr * NBUCK + b) * TBL;
        if (t < TBL - 1) tb[t] = base + hist[(t >> 3) * BSZ + (t & 7) * SUB];
        if (t == TBL - 1) tb[t] = base + cnt;
    }
    __syncthreads();
    // scatter (hist becomes cursors); KEEP full payload
    for (int i = t; i < cnt; i += 256) {
        int v = (i < CAP) ? staged[i] : reg[i];
        int key = ((v & 0x1FFFF) >> 13) * BSZ + (v >> 17);
        int p = atomicAdd(&hist[key], 1);
        reg[p] = v;
    }
}

__global__ __launch_bounds__(256) void k_rsqrt(const int* __restrict__ deg,
                                               float* __restrict__ rs) {
    int i = blockIdx.x * 256 + threadIdx.x;
    if (i >= 12 * N_NODES) return;
    int v = deg[i];
    rs[i] = rsqrtf((float)(v < 1 ? 1 : v));
}

// ---------------- x -> fp16 ----------------
__global__ __launch_bounds__(256) void k_cvt_x(const float* __restrict__ x,
                                               _Float16* __restrict__ xh) {
    int i = blockIdx.x * 256 + threadIdx.x;
    if (i >= N_NODES * 64) return;
    float2 v = ((const float2*)x)[i];
    half2v h; h.x = (_Float16)v.x; h.y = (_Float16)v.y;
    ((half2v*)xh)[i] = h;
}

// ---------------- W1/W2 -> fp16 fragment order ----------------
__global__ __launch_bounds__(256) void k_repack(const float* __restrict__ W1,
                                                const float* __restrict__ W2,
                                                _Float16* __restrict__ W1f,
                                                _Float16* __restrict__ W2f) {
    int i = blockIdx.x * 256 + threadIdx.x;
    if (i < 96 * 512) {
        int g = i >> 9, rem = i & 511, L = rem >> 3, j = rem & 7;
        int kc = g >> 3, nt = g & 7;
        int k = kc * 32 + (L >> 4) * 8 + j;
        int n = nt * 16 + (L & 15);
        W1f[i] = (_Float16)W1[k * 128 + n];
    } else if (i < 96 * 512 + 48 * 512) {
        int ii = i - 96 * 512;
        int g = ii >> 9, rem = ii & 511, L = rem >> 3, j = rem & 7;
        int kc = g / 12, nt = g % 12;
        int k = kc * 32 + (L >> 4) * 8 + j;
        int n = nt * 16 + (L & 15);
        int r = n >> 6, c = n & 63;
        W2f[ii] = (_Float16)W2[r * 8192 + k * 64 + c];
    }
}

// ---------------- layer-1 pull: tile-phased, bucket-major, LDS accumulators -------------
// block = (bucket b, sub-bucket s of 50 dsts, feature-half f). Tile-outer loop keeps the
// live x slice at 2 MB (fits per-XCD L2) chip-wide.
__global__ __launch_bounds__(256) void k_pull1(const int* __restrict__ pairs,
                                               const int* __restrict__ tstart,
                                               const float* __restrict__ rs,
                                               const _Float16* __restrict__ xh,
                                               _Float16* __restrict__ agg) {
    int b = blockIdx.x;
    int yy = blockIdx.y;
    int s = yy & 7, f = yy >> 3;
    int tid = threadIdx.x;
    int wid = tid >> 6, lane = tid & 63;
    __shared__ float acc[3 * SUB * 64];     // 38.4 KB
    for (int i = tid; i < 3 * SUB * 64; i += 256) acc[i] = 0.f;
    __syncthreads();
    const _Float16* xcol = xh + f * 64 + lane;
    for (int t = 0; t < NTILE; t++) {
#pragma unroll
        for (int rel = 0; rel < 3; rel++) {
            const int* tb = tstart + (size_t)(rel * NBUCK + b) * TBL;
            int e = t * 8 + s;
            int e0 = tb[e], e1 = tb[e + 1];
            const int* pr = pairs + (size_t)rel * N_EDGES;
            const float* rsr = rs + (size_t)rel * N_NODES;
            float* accr = acc + rel * SUB * 64;
            int len = e1 - e0;
            int w0 = e0 + ((len * wid) >> 2);
            int w1 = e0 + ((len * (wid + 1)) >> 2);
            for (int bb = w0; bb < w1; bb += 64) {
                int c = w1 - bb; if (c > 64) c = 64;
                int v_l = (lane < c) ? pr[bb + lane] : 0;
                float w_l = (lane < c) ? rsr[v_l & 0x1FFFF] : 0.f;
                int qq = 0;
                for (; qq + 8 <= c; qq += 8) {
                    int sv[8]; float ww[8]; _Float16 vv[8];
#pragma unroll
                    for (int u = 0; u < 8; u++) {
                        sv[u] = __shfl(v_l, qq + u);
                        ww[u] = __shfl(w_l, qq + u);
                    }
#pragma unroll
                    for (int u = 0; u < 8; u++)
                        vv[u] = xcol[(size_t)(sv[u] & 0x1FFFF) * 128];
#pragma unroll
                    for (int u = 0; u < 8; u++) {
                        int dq = (sv[u] >> 17) - s * SUB;
                        atomicAdd(&accr[dq * 64 + lane], ww[u] * (float)vv[u]);
                    }
                }
                for (; qq < c; qq++) {
                    int sv = __shfl(v_l, qq);
                    float w = __shfl(w_l, qq);
                    _Float16 v = xcol[(size_t)(sv & 0x1FFFF) * 128];
                    int dq = (sv >> 17) - s * SUB;
                    atomicAdd(&accr[dq * 64 + lane], w * (float)v);
                }
            }
        }
        __syncthreads();   // keep waves tile-phase aligned
    }
    // epilogue: scale by rs_in, write agg fragment layout
    for (int i = tid; i < 3 * SUB * 64; i += 256) {
        int rel = i / (SUB * 64);
        int rem = i - rel * (SUB * 64);
        int dq = rem >> 6, ft = rem & 63;
        int dst = b * BSZ + s * SUB + dq;
        float sc = rs[(size_t)(3 + rel) * N_NODES + dst];
        int k = rel * 128 + f * 64 + ft;
        size_t idx = (size_t)(dst >> 4) * 48 * 128 + (size_t)(k >> 3) * 128 +
                     (dst & 15) * 8 + (k & 7);
        agg[idx] = (_Float16)(acc[i] * sc);
    }
}

// ---------------- fused MFMA GEMM + rs_out(layer1) fold into per-rel hW ----------------
__global__ __launch_bounds__(256) void k_gemm12(const _Float16* __restrict__ Af,
                                                const _Float16* __restrict__ W1f,
                                                const float* __restrict__ b1,
                                                const _Float16* __restrict__ W2f,
                                                const float* __restrict__ rs1out,
                                                _Float16* __restrict__ hW) {
    __shared__ _Float16 Hs[4][2048];
    int tid = threadIdx.x;
    int w = tid >> 6, L = tid & 63;
    int mt = blockIdx.x * 4 + w;
    if (mt >= MTILES) return;
    const half8* A8 = (const half8*)Af;
    const half8* B1 = (const half8*)W1f;
    const half8* B2 = (const half8*)W2f;

    floatx4 acc[8];
#pragma unroll
    for (int nt = 0; nt < 8; nt++) acc[nt] = (floatx4)(0.f);
#pragma unroll
    for (int kc = 0; kc < 12; kc++) {
        half8 a = A8[(size_t)mt * 768 + kc * 64 + L];
#pragma unroll
        for (int nt = 0; nt < 8; nt++) {
            half8 b = B1[(kc * 8 + nt) * 64 + L];
            acc[nt] = __builtin_amdgcn_mfma_f32_16x16x32_f16(a, b, acc[nt], 0, 0, 0);
        }
    }
    int cl = L & 15, rw = L >> 4;
#pragma unroll
    for (int nt = 0; nt < 8; nt++) {
        int n = nt * 16 + cl;
        float bs = b1[n] + b1[128 + n] + b1[256 + n];
#pragma unroll
        for (int j = 0; j < 4; j++) {
            int mm = rw * 4 + j;
            float v = acc[nt][j] + bs;
            v = v > 0.f ? v : 0.f;
            Hs[w][(n >> 3) * 128 + mm * 8 + (n & 7)] = (_Float16)v;
        }
    }
    __syncthreads();

    const half8* H8 = (const half8*)(&Hs[w][0]);
    floatx4 acc2[12];
#pragma unroll
    for (int nt = 0; nt < 12; nt++) acc2[nt] = (floatx4)(0.f);
#pragma unroll
    for (int kc = 0; kc < 4; kc++) {
        half8 a = H8[kc * 64 + L];
#pragma unroll
        for (int nt = 0; nt < 12; nt++) {
            half8 b = B2[(kc * 12 + nt) * 64 + L];
            acc2[nt] = __builtin_amdgcn_mfma_f32_16x16x32_f16(a, b, acc2[nt], 0, 0, 0);
        }
    }
#pragma unroll
    for (int j = 0; j < 4; j++) {
        int mm = mt * 16 + rw * 4 + j;
        float wr[3] = {rs1out[mm], rs1out[N_NODES + mm], rs1out[2 * N_NODES + mm]};
#pragma unroll
        for (int nt = 0; nt < 12; nt++) {
            int n = nt * 16 + cl;
            int rel = nt >> 2, c = n & 63;
            hW[(size_t)rel * (N_NODES * 64) + (size_t)mm * 64 + c] =
                (_Float16)(acc2[nt][j] * wr[rel]);
        }
    }
}

// ---------------- layer-2 pull: tile-phased, bucket-major, rs_in folded per edge --------
// block = (bucket b, sub-bucket s). Single fp32 accumulator (rels merged via per-edge
// scale). rel-outer: live hW slice per tile = 1 MB.
__global__ __launch_bounds__(256) void k_pull2(const int* __restrict__ pairs,
                                               const int* __restrict__ tstart,
                                               const float* __restrict__ rs,
                                               const _Float16* __restrict__ hW,
                                               const float* __restrict__ b2,
                                               float* __restrict__ out) {
    int b = blockIdx.x;
    int s = blockIdx.y;
    int tid = threadIdx.x;
    int wid = tid >> 6, lane = tid & 63;
    __shared__ float acc[SUB * 64];         // 12.8 KB
    for (int i = tid; i < SUB * 64; i += 256) acc[i] = 0.f;
    __syncthreads();
#pragma unroll
    for (int rel = 0; rel < 3; rel++) {
        const int* tb = tstart + (size_t)((3 + rel) * NBUCK + b) * TBL;
        const int* pr = pairs + (size_t)(3 + rel) * N_EDGES;
        const _Float16* hcol = hW + (size_t)rel * (N_NODES * 64) + lane;
        const float* rsd = rs + (size_t)(9 + rel) * N_NODES + b * BSZ;
        for (int t = 0; t < NTILE; t++) {
            int e = t * 8 + s;
            int e0 = tb[e], e1 = tb[e + 1];
            int len = e1 - e0;
            int w0 = e0 + ((len * wid) >> 2);
            int w1 = e0 + ((len * (wid + 1)) >> 2);
            for (int bb = w0; bb < w1; bb += 64) {
                int c = w1 - bb; if (c > 64) c = 64;
                int v_l = (lane < c) ? pr[bb + lane] : 0;
                float w_l = (lane < c) ? rsd[v_l >> 17] : 0.f;
                int qq = 0;
                for (; qq + 8 <= c; qq += 8) {
                    int sv[8]; float ww[8]; _Float16 vv[8];
#pragma unroll
                    for (int u = 0; u < 8; u++) {
                        sv[u] = __shfl(v_l, qq + u);
                        ww[u] = __shfl(w_l, qq + u);
                    }
#pragma unroll
                    for (int u = 0; u < 8; u++)
                        vv[u] = hcol[(size_t)(sv[u] & 0x1FFFF) * 64];
#pragma unroll
                    for (int u = 0; u < 8; u++) {
                        int dq = (sv[u] >> 17) - s * SUB;
                        atomicAdd(&acc[dq * 64 + lane], ww[u] * (float)vv[u]);
                    }
                }
                for (; qq < c; qq++) {
                    int sv = __shfl(v_l, qq);
                    float w = __shfl(w_l, qq);
                    _Float16 v = hcol[(size_t)(sv & 0x1FFFF) * 64];
                    int dq = (sv >> 17) - s * SUB;
                    atomicAdd(&acc[dq * 64 + lane], w * (float)v);
                }
            }
            __syncthreads();
        }
    }
    for (int i = tid; i < SUB * 64; i += 256) {
        int dq = i >> 6, ft = i & 63;
        int dst = b * BSZ + s * SUB + dq;
        out[(size_t)dst * 64 + ft] = acc[i] + b2[ft] + b2[64 + ft] + b2[128 + ft];
    }
}

extern "C" void kernel_launch(void* const* d_in, const int* in_sizes, int n_in,
                              void* d_out, int out_size, void* d_ws, size_t ws_size,
                              hipStream_t stream) {
    (void)in_sizes; (void)n_in; (void)out_size; (void)ws_size;
    const float* x  = (const float*)d_in[0];
    const float* W1 = (const float*)d_in[1];
    const float* b1 = (const float*)d_in[2];
    const float* W2 = (const float*)d_in[3];
    const float* b2 = (const float*)d_in[4];
    const int*   ei = (const int*)d_in[5];
    float* out = (float*)d_out;

    char* ws = (char*)d_ws;
    int*      deg     = (int*)(ws + OFF_DEG);
    int*      gcount  = (int*)(ws + OFF_GC);
    int*      bbase   = (int*)(ws + OFF_BB);
    int*      bcursor = (int*)(ws + OFF_BC);
    float*    rs      = (float*)(ws + OFF_RS);
    int*      tstart  = (int*)(ws + OFF_START);
    int*      pairs   = (int*)(ws + OFF_PAIRS);
    _Float16* xh      = (_Float16*)(ws + OFF_XH);
    _Float16* W1f     = (_Float16*)(ws + OFF_W1F);
    _Float16* W2f     = (_Float16*)(ws + OFF_W2F);
    _Float16* agg     = (_Float16*)(ws + OFF_AGG);
    _Float16* hW      = (_Float16*)(ws + OFF_HW);
    short*    dds     = (short*)(ws + OFF_DDS);
    int*      gcount_s= (int*)(ws + OFF_GCS);
    int*      bbase_s = (int*)(ws + OFF_BBS);
    int*      bcursor_s=(int*)(ws + OFF_BCS);
    int*      chd     = (int*)(ws + OFF_CHD);
    int*      chs     = (int*)(ws + OFF_CHS);

    hipMemsetAsync(gcount, 0, 6144, stream);
    hipMemsetAsync(gcount_s, 0, 6144, stream);

    k_cvt_x<<<25000, 256, 0, stream>>>(x, xh);
    k_repack<<<288, 256, 0, stream>>>(W1, W2, W1f, W2f);
    k_bhist2<<<dim3(NCHUNK, 6), 256, 0, stream>>>(ei, gcount, gcount_s, chd, chs);
    k_bscan2<<<12, 256, 0, stream>>>(gcount, gcount_s, bbase, bcursor, bbase_s, bcursor_s);
    k_bpart<<<dim3(NCHUNK, 6), 256, 0, stream>>>(ei, chd, bcursor, pairs);
    k_bpart_s<<<dim3(NCHUNK, 6), 256, 0, stream>>>(ei, chs, bcursor_s, dds);
    k_bsort<<<dim3(NBUCK, 6), 256, 0, stream>>>(bbase, pairs, tstart, deg);
    k_bcount_s<<<dim3(NBUCK, 6), 256, 0, stream>>>(bbase_s, dds, deg);
    k_rsqrt<<<4688, 256, 0, stream>>>(deg, rs);
    k_pull1<<<dim3(NBUCK, 16), 256, 0, stream>>>(pairs, tstart, rs, xh, agg);
    k_gemm12<<<(MTILES + 3) / 4, 256, 0, stream>>>(agg, W1f, b1, W2f,
                                                   rs + 6 * (size_t)N_NODES, hW);
    k_pull2<<<dim3(NBUCK, 8), 256, 0, stream>>>(pairs, tstart, rs, hW, b2, out);
}

// Round 4
// 741.458 us; speedup vs baseline: 7.3112x; 7.3112x over previous
//
#include <hip/hip_runtime.h>

#define N_NODES 100000
#define N_EDGES 1600000
#define NBUCK 250          // buckets per (layer,rel)
#define BSZ 400            // nodes per bucket (250*400 = 100000)
#define CHUNK 8192         // edges per partition block
#define NCHUNK 196         // ceil(E/CHUNK)
#define CAP 8192           // LDS staging capacity in k_bsort
#define MTILES 6250        // N_NODES / 16
#define NTILE 13           // src tiles of 8192 rows (100000 >> 13 -> 0..12)
#define NKEY (BSZ * NTILE) // 5200 sort bins
#define NKEYP 5376         // padded to 21*256

typedef _Float16 half8 __attribute__((ext_vector_type(8)));
typedef _Float16 half2v __attribute__((ext_vector_type(2)));
typedef float floatx4 __attribute__((ext_vector_type(4)));

// workspace layout (bytes), total ~191.4 MB:
#define OFF_DEG   0ull           // 12N int: per layer, out r0..2 then in r0..2
#define OFF_GC    4800000ull     // 1500 int (pad 6144) dst-bucket counts
#define OFF_BB    4806144ull     // dst bucket bases
#define OFF_BC    4812288ull     // dst bucket cursors
#define OFF_RS    4818432ull     // 12N float
#define OFF_START 9618432ull     // 6N int
#define OFF_PAIRS 12018432ull    // 6E int
#define OFF_XH    50418432ull    // N*128 fp16 (row-major)
#define OFF_W1F   76018432ull    // 96*512 fp16 (frag order)
#define OFF_W2F   76116736ull    // 48*512 fp16 (frag order)
#define OFF_AGG   76165888ull    // N*384 fp16, A-frag layout; head reused as scratch
#define OFF_HW    152965888ull   // N*192 fp16, row-major (pre-scaled by rs_out layer1)

// scratch aliased into agg region (dead until k_pull1):
#define OFF_DDS   OFF_AGG                    // 6E short = 19.2 MB
#define OFF_GCS   (OFF_AGG + 19200000ull)    // 1500 int (pad 6144)
#define OFF_BBS   (OFF_AGG + 19206144ull)    // 1500 int
#define OFF_BCS   (OFF_AGG + 19212288ull)    // 1500 int
#define OFF_CHD   (OFF_AGG + 19218432ull)    // per-chunk dst hists: 6*196*256 int
#define OFF_CHS   (OFF_AGG + 20422656ull)    // per-chunk src hists

__device__ __forceinline__ void lds_scan256(int* a) {
    int t = threadIdx.x;
    for (int off = 1; off < 256; off <<= 1) {
        int v = (t >= off) ? a[t - off] : 0;
        __syncthreads();
        a[t] += v;
        __syncthreads();
    }
}

// ---------------- fused bucket histograms of src AND dst (+ per-chunk saves) -------------
__global__ __launch_bounds__(256) void k_bhist2(const int* __restrict__ ei,
                                                int* __restrict__ gcount_d,
                                                int* __restrict__ gcount_s,
                                                int* __restrict__ chd,
                                                int* __restrict__ chs) {
    int lr = blockIdx.y;
    int cx = blockIdx.x;
    int e0 = cx * CHUNK;
    int n = min(CHUNK, N_EDGES - e0);
    const int* bs = ei + (size_t)lr * 2 * N_EDGES + e0;
    const int* bd = bs + N_EDGES;
    __shared__ int lhs[256];
    __shared__ int lhd[256];
    int t = threadIdx.x;
    lhs[t] = 0; lhd[t] = 0;
    __syncthreads();
    for (int i = t; i < n; i += 256) {
        atomicAdd(&lhs[bs[i] / BSZ], 1);
        atomicAdd(&lhd[bd[i] / BSZ], 1);
    }
    __syncthreads();
    chd[(lr * NCHUNK + cx) * 256 + t] = lhd[t];
    chs[(lr * NCHUNK + cx) * 256 + t] = lhs[t];
    if (t < NBUCK) {
        if (lhd[t]) atomicAdd(&gcount_d[lr * NBUCK + t], lhd[t]);
        if (lhs[t]) atomicAdd(&gcount_s[lr * NBUCK + t], lhs[t]);
    }
}

// ---------------- scan bucket counts (dst q 0..5, src q 6..11) ----------------
__global__ __launch_bounds__(256) void k_bscan2(const int* __restrict__ gc_d,
                                                const int* __restrict__ gc_s,
                                                int* __restrict__ bb_d,
                                                int* __restrict__ bc_d,
                                                int* __restrict__ bb_s,
                                                int* __restrict__ bc_s) {
    int q = blockIdx.x, t = threadIdx.x;
    int lr = (q < 6) ? q : q - 6;
    const int* gc = (q < 6) ? gc_d : gc_s;
    int* bb = (q < 6) ? bb_d : bb_s;
    int* bc = (q < 6) ? bc_d : bc_s;
    __shared__ int a[256];
    int v = (t < NBUCK) ? gc[lr * NBUCK + t] : 0;
    a[t] = v;
    __syncthreads();
    lds_scan256(a);
    if (t < NBUCK) {
        int excl = a[t] - v;
        bb[lr * NBUCK + t] = excl;
        bc[lr * NBUCK + t] = excl;
    }
}

// ---------------- partition edges into dst buckets (payload src|dd<<17) ----------------
__global__ __launch_bounds__(256) void k_bpart(const int* __restrict__ ei,
                                               const int* __restrict__ chd,
                                               int* __restrict__ bcursor,
                                               int* __restrict__ pairs) {
    int lr = blockIdx.y;
    int cx = blockIdx.x;
    int e0 = cx * CHUNK;
    int n = min(CHUNK, N_EDGES - e0);
    const int* bs = ei + (size_t)lr * 2 * N_EDGES + e0;
    const int* bd = bs + N_EDGES;
    __shared__ int lh[256];
    __shared__ int lexcl[256];
    __shared__ int lcur[256];
    __shared__ int gb[256];
    __shared__ int staged[CHUNK];
    __shared__ unsigned char stb[CHUNK];
    int t = threadIdx.x;
    int cnt_t = chd[(lr * NCHUNK + cx) * 256 + t];
    lh[t] = cnt_t;
    __syncthreads();
    lds_scan256(lh);
    int excl_t = lh[t] - cnt_t;
    lexcl[t] = excl_t;
    lcur[t] = excl_t;
    if (t < NBUCK) gb[t] = cnt_t ? atomicAdd(&bcursor[lr * NBUCK + t], cnt_t) : 0;
    __syncthreads();
    for (int i = t; i < n; i += 256) {
        int s = bs[i], d = bd[i];
        int b = d / BSZ;
        int dd = d - b * BSZ;
        int p = atomicAdd(&lcur[b], 1);
        staged[p] = s | (dd << 17);
        stb[p] = (unsigned char)b;
    }
    __syncthreads();
    int* outp = pairs + (size_t)lr * N_EDGES;
    for (int i = t; i < n; i += 256) {
        int b = stb[i];
        outp[gb[b] + (i - lexcl[b])] = staged[i];
    }
}

// ---------------- partition src into buckets (payload = in-bucket offset) ----------------
__global__ __launch_bounds__(256) void k_bpart_s(const int* __restrict__ ei,
                                                 const int* __restrict__ chs,
                                                 int* __restrict__ bcursor_s,
                                                 short* __restrict__ dds) {
    int lr = blockIdx.y;
    int cx = blockIdx.x;
    int e0 = cx * CHUNK;
    int n = min(CHUNK, N_EDGES - e0);
    const int* bs = ei + (size_t)lr * 2 * N_EDGES + e0;
    __shared__ int lh[256];
    __shared__ int lexcl[256];
    __shared__ int lcur[256];
    __shared__ int gb[256];
    __shared__ short staged[CHUNK];
    __shared__ unsigned char stb[CHUNK];
    int t = threadIdx.x;
    int cnt_t = chs[(lr * NCHUNK + cx) * 256 + t];
    lh[t] = cnt_t;
    __syncthreads();
    lds_scan256(lh);
    int excl_t = lh[t] - cnt_t;
    lexcl[t] = excl_t;
    lcur[t] = excl_t;
    if (t < NBUCK) gb[t] = cnt_t ? atomicAdd(&bcursor_s[lr * NBUCK + t], cnt_t) : 0;
    __syncthreads();
    for (int i = t; i < n; i += 256) {
        int s = bs[i];
        int b = s / BSZ;
        int p = atomicAdd(&lcur[b], 1);
        staged[p] = (short)(s - b * BSZ);
        stb[p] = (unsigned char)b;
    }
    __syncthreads();
    short* outp = dds + (size_t)lr * N_EDGES;
    for (int i = t; i < n; i += 256) {
        int b = stb[i];
        outp[gb[b] + (i - lexcl[b])] = staged[i];
    }
}

// ------------ per-bucket src count -> out-degree + rs_out (fused rsqrt) ------------
__global__ __launch_bounds__(256) void k_bcount_s(const int* __restrict__ bbase_s,
                                                  const short* __restrict__ dds,
                                                  int* __restrict__ deg,
                                                  float* __restrict__ rs) {
    int lr = blockIdx.y, b = blockIdx.x;
    int layer = lr / 3, r = lr % 3;
    int base = bbase_s[lr * NBUCK + b];
    int next = (b < NBUCK - 1) ? bbase_s[lr * NBUCK + b + 1] : N_EDGES;
    int cnt = next - base;
    const short* reg = dds + (size_t)lr * N_EDGES + base;
    __shared__ int h[BSZ];
    int t = threadIdx.x;
    h[t] = 0;
    if (t < BSZ - 256) h[t + 256] = 0;
    __syncthreads();
    for (int i = t; i < cnt; i += 256)
        atomicAdd(&h[reg[i]], 1);
    __syncthreads();
    size_t doff = (size_t)layer * 6 * N_NODES + (size_t)r * N_NODES + b * BSZ;
    int* degout = deg + doff;
    float* rsout = rs + doff;
    degout[t] = h[t];
    rsout[t] = rsqrtf((float)(h[t] < 1 ? 1 : h[t]));
    if (t < BSZ - 256) {
        degout[t + 256] = h[t + 256];
        rsout[t + 256] = rsqrtf((float)(h[t + 256] < 1 ? 1 : h[t + 256]));
    }
}

// ------ per-bucket counting sort by (dd, src-tile) + CSR + in-degree + rs_in ------
__global__ __launch_bounds__(256) void k_bsort(const int* __restrict__ bbase,
                                               int* __restrict__ pairs,
                                               int* __restrict__ start,
                                               int* __restrict__ deg,
                                               float* __restrict__ rs) {
    int lr = blockIdx.y, b = blockIdx.x;
    int layer = lr / 3, r = lr % 3;
    int base = bbase[lr * NBUCK + b];
    int next = (b < NBUCK - 1) ? bbase[lr * NBUCK + b + 1] : N_EDGES;
    int cnt = next - base;
    int* reg = pairs + (size_t)lr * N_EDGES + base;
    __shared__ int staged[CAP];      // 32 KB
    __shared__ int hist[NKEYP];      // 21.5 KB: counts -> exclusive starts -> cursors
    __shared__ int tsum[256];
    int t = threadIdx.x;
    for (int i = t; i < NKEYP; i += 256) hist[i] = 0;
    __syncthreads();
    for (int i = t; i < cnt; i += 256) {
        int v = reg[i];
        if (i < CAP) staged[i] = v;
        int key = (v >> 17) * NTILE + ((v & 0x1FFFF) >> 13);
        atomicAdd(&hist[key], 1);
    }
    __syncthreads();
    // scan 5376 bins: thread t owns bins [t*21, t*21+21)
    int b0 = t * 21;
    int loc[21];
    int s = 0;
#pragma unroll
    for (int k = 0; k < 21; k++) { loc[k] = s; s += hist[b0 + k]; }
    tsum[t] = s;
    __syncthreads();
    lds_scan256(tsum);               // inclusive
    int tbase = tsum[t] - s;
#pragma unroll
    for (int k = 0; k < 21; k++) hist[b0 + k] = tbase + loc[k];
    __syncthreads();
    // CSR start + in-degree + rs_in from bin boundaries (hist[5200] == cnt via zero pad)
    int d0 = b * BSZ;
    {
        size_t doff = (size_t)layer * 6 * N_NODES + (size_t)(3 + r) * N_NODES + d0;
        int st = hist[t * NTILE];
        int en = hist[(t + 1) * NTILE];
        start[(size_t)lr * N_NODES + d0 + t] = base + st;
        int dg = en - st;
        deg[doff + t] = dg;
        rs[doff + t] = rsqrtf((float)(dg < 1 ? 1 : dg));
        if (t < BSZ - 256) {
            int t2 = t + 256;
            int st2 = hist[t2 * NTILE];
            int en2 = hist[(t2 + 1) * NTILE];
            start[(size_t)lr * N_NODES + d0 + t2] = base + st2;
            int dg2 = en2 - st2;
            deg[doff + t2] = dg2;
            rs[doff + t2] = rsqrtf((float)(dg2 < 1 ? 1 : dg2));
        }
    }
    __syncthreads();
    // scatter (hist becomes cursors)
    for (int i = t; i < cnt; i += 256) {
        int v = (i < CAP) ? staged[i] : reg[i];
        int key = (v >> 17) * NTILE + ((v & 0x1FFFF) >> 13);
        int p = atomicAdd(&hist[key], 1);
        reg[p] = v & 0x1FFFF;
    }
}

// ---------------- x -> fp16 ----------------
__global__ __launch_bounds__(256) void k_cvt_x(const float* __restrict__ x,
                                               _Float16* __restrict__ xh) {
    int i = blockIdx.x * 256 + threadIdx.x;
    if (i >= N_NODES * 64) return;
    float2 v = ((const float2*)x)[i];
    half2v h; h.x = (_Float16)v.x; h.y = (_Float16)v.y;
    ((half2v*)xh)[i] = h;
}

// ---------------- W1/W2 -> fp16 fragment order ----------------
__global__ __launch_bounds__(256) void k_repack(const float* __restrict__ W1,
                                                const float* __restrict__ W2,
                                                _Float16* __restrict__ W1f,
                                                _Float16* __restrict__ W2f) {
    int i = blockIdx.x * 256 + threadIdx.x;
    if (i < 96 * 512) {
        int g = i >> 9, rem = i & 511, L = rem >> 3, j = rem & 7;
        int kc = g >> 3, nt = g & 7;
        int k = kc * 32 + (L >> 4) * 8 + j;
        int n = nt * 16 + (L & 15);
        W1f[i] = (_Float16)W1[k * 128 + n];
    } else if (i < 96 * 512 + 48 * 512) {
        int ii = i - 96 * 512;
        int g = ii >> 9, rem = ii & 511, L = rem >> 3, j = rem & 7;
        int kc = g / 12, nt = g % 12;
        int k = kc * 32 + (L >> 4) * 8 + j;
        int n = nt * 16 + (L & 15);
        int r = n >> 6, c = n & 63;
        W2f[ii] = (_Float16)W2[r * 8192 + k * 64 + c];
    }
}

// ---------------- per-relation gather accumulate (chunked shfl-broadcast, unroll-8) ------
__device__ __forceinline__ void accum_rel1(const int* __restrict__ sorted, int j, int n,
                                           const float* __restrict__ rsrow,
                                           const half2v* __restrict__ x2,
                                           int lane, float2& acc) {
    for (int base = 0; base < n; base += 64) {
        int c = n - base; if (c > 64) c = 64;
        int s_l = (lane < c) ? sorted[j + base + lane] : 0;
        float w_l = (lane < c) ? rsrow[s_l] : 0.f;
        int q = 0;
        for (; q + 8 <= c; q += 8) {
            int ss[8]; float ww[8]; half2v vv[8];
#pragma unroll
            for (int u = 0; u < 8; u++) { ss[u] = __shfl(s_l, q + u); ww[u] = __shfl(w_l, q + u); }
#pragma unroll
            for (int u = 0; u < 8; u++) vv[u] = x2[(size_t)ss[u] * 64 + lane];
#pragma unroll
            for (int u = 0; u < 8; u++) {
                acc.x += ww[u] * (float)vv[u].x;
                acc.y += ww[u] * (float)vv[u].y;
            }
        }
        for (; q < c; q++) {
            int s = __shfl(s_l, q); float w = __shfl(w_l, q);
            half2v v = x2[(size_t)s * 64 + lane];
            acc.x += w * (float)v.x; acc.y += w * (float)v.y;
        }
    }
}

// ---------------- layer-1 pull ----------------
__global__ __launch_bounds__(256) void k_pull1(const int* __restrict__ sorted,
                                               const int* __restrict__ start,
                                               const int* __restrict__ deg,
                                               const float* __restrict__ rs,
                                               const _Float16* __restrict__ xh,
                                               _Float16* __restrict__ agg) {
    int wid = threadIdx.x >> 6, lane = threadIdx.x & 63;
    int dst = blockIdx.x * 4 + wid;
    if (dst >= N_NODES) return;
    const half2v* x2 = (const half2v*)xh;
    const int* deg0in = deg + 3 * N_NODES;
    float2 a0 = make_float2(0.f, 0.f), a1 = a0, a2 = a0;
    accum_rel1(sorted, start[dst], deg0in[dst], rs, x2, lane, a0);
    accum_rel1(sorted + N_EDGES, start[N_NODES + dst], deg0in[N_NODES + dst],
               rs + N_NODES, x2, lane, a1);
    accum_rel1(sorted + 2 * N_EDGES, start[2 * N_NODES + dst], deg0in[2 * N_NODES + dst],
               rs + 2 * N_NODES, x2, lane, a2);
    size_t mbase = (size_t)(dst >> 4) * 48 * 128;
    int moff = (dst & 15) * 8;
#pragma unroll
    for (int r = 0; r < 3; r++) {
        float2 a = (r == 0) ? a0 : (r == 1) ? a1 : a2;
        float w = rs[(size_t)(3 + r) * N_NODES + dst];
        int k = r * 128 + 2 * lane;
        size_t idx = mbase + (size_t)(k >> 3) * 128 + moff + (k & 7);
        half2v h; h.x = (_Float16)(a.x * w); h.y = (_Float16)(a.y * w);
        *(half2v*)(agg + idx) = h;
    }
}

// ---------------- fused MFMA GEMM + rs_out(layer1) fold into hW ----------------
__global__ __launch_bounds__(256) void k_gemm12(const _Float16* __restrict__ Af,
                                                const _Float16* __restrict__ W1f,
                                                const float* __restrict__ b1,
                                                const _Float16* __restrict__ W2f,
                                                const float* __restrict__ rs1out,
                                                _Float16* __restrict__ hW) {
    __shared__ _Float16 Hs[4][2048];
    int tid = threadIdx.x;
    int w = tid >> 6, L = tid & 63;
    int mt = blockIdx.x * 4 + w;
    if (mt >= MTILES) return;
    const half8* A8 = (const half8*)Af;
    const half8* B1 = (const half8*)W1f;
    const half8* B2 = (const half8*)W2f;

    floatx4 acc[8];
#pragma unroll
    for (int nt = 0; nt < 8; nt++) acc[nt] = (floatx4)(0.f);
#pragma unroll
    for (int kc = 0; kc < 12; kc++) {
        half8 a = A8[(size_t)mt * 768 + kc * 64 + L];
#pragma unroll
        for (int nt = 0; nt < 8; nt++) {
            half8 b = B1[(kc * 8 + nt) * 64 + L];
            acc[nt] = __builtin_amdgcn_mfma_f32_16x16x32_f16(a, b, acc[nt], 0, 0, 0);
        }
    }
    int cl = L & 15, rw = L >> 4;
#pragma unroll
    for (int nt = 0; nt < 8; nt++) {
        int n = nt * 16 + cl;
        float bs = b1[n] + b1[128 + n] + b1[256 + n];
#pragma unroll
        for (int j = 0; j < 4; j++) {
            int mm = rw * 4 + j;
            float v = acc[nt][j] + bs;
            v = v > 0.f ? v : 0.f;
            Hs[w][(n >> 3) * 128 + mm * 8 + (n & 7)] = (_Float16)v;
        }
    }
    __syncthreads();

    const half8* H8 = (const half8*)(&Hs[w][0]);
    floatx4 acc2[12];
#pragma unroll
    for (int nt = 0; nt < 12; nt++) acc2[nt] = (floatx4)(0.f);
#pragma unroll
    for (int kc = 0; kc < 4; kc++) {
        half8 a = H8[kc * 64 + L];
#pragma unroll
        for (int nt = 0; nt < 12; nt++) {
            half8 b = B2[(kc * 12 + nt) * 64 + L];
            acc2[nt] = __builtin_amdgcn_mfma_f32_16x16x32_f16(a, b, acc2[nt], 0, 0, 0);
        }
    }
#pragma unroll
    for (int j = 0; j < 4; j++) {
        int mm = mt * 16 + rw * 4 + j;
        float wr[3] = {rs1out[mm], rs1out[N_NODES + mm], rs1out[2 * N_NODES + mm]};
#pragma unroll
        for (int nt = 0; nt < 12; nt++) {
            int n = nt * 16 + cl;
            hW[(size_t)mm * 192 + n] = (_Float16)(acc2[nt][j] * wr[nt >> 2]);
        }
    }
}

// ---------------- layer-2 per-relation gather (pre-scaled hW) ----------------
__device__ __forceinline__ void accum_rel2(const int* __restrict__ sorted, int j, int n,
                                           const _Float16* __restrict__ hWr,
                                           int lane, float& acc) {
    for (int base = 0; base < n; base += 64) {
        int c = n - base; if (c > 64) c = 64;
        int s_l = (lane < c) ? sorted[j + base + lane] : 0;
        int q = 0;
        for (; q + 8 <= c; q += 8) {
            int ss[8]; _Float16 vv[8];
#pragma unroll
            for (int u = 0; u < 8; u++) ss[u] = __shfl(s_l, q + u);
#pragma unroll
            for (int u = 0; u < 8; u++) vv[u] = hWr[(size_t)ss[u] * 192 + lane];
#pragma unroll
            for (int u = 0; u < 8; u++) acc += (float)vv[u];
        }
        for (; q < c; q++) {
            int s = __shfl(s_l, q);
            acc += (float)hWr[(size_t)s * 192 + lane];
        }
    }
}

// ---------------- layer-2 pull ----------------
__global__ __launch_bounds__(256) void k_pull2(const int* __restrict__ sorted1,
                                               const int* __restrict__ start1,
                                               const int* __restrict__ deg1,
                                               const float* __restrict__ rs1,
                                               const _Float16* __restrict__ hW,
                                               const float* __restrict__ b2,
                                               float* __restrict__ out) {
    int wid = threadIdx.x >> 6, lane = threadIdx.x & 63;
    int dst = blockIdx.x * 4 + wid;
    if (dst >= N_NODES) return;
    const int* deg1in = deg1 + 3 * N_NODES;
    float a0 = 0.f, a1 = 0.f, a2 = 0.f;
    accum_rel2(sorted1, start1[dst], deg1in[dst], hW, lane, a0);
    accum_rel2(sorted1 + N_EDGES, start1[N_NODES + dst], deg1in[N_NODES + dst],
               hW + 64, lane, a1);
    accum_rel2(sorted1 + 2 * N_EDGES, start1[2 * N_NODES + dst], deg1in[2 * N_NODES + dst],
               hW + 128, lane, a2);
    float o = a0 * rs1[3 * N_NODES + dst] + a1 * rs1[4 * N_NODES + dst] +
              a2 * rs1[5 * N_NODES + dst] + b2[lane] + b2[64 + lane] + b2[128 + lane];
    out[(size_t)dst * 64 + lane] = o;
}

extern "C" void kernel_launch(void* const* d_in, const int* in_sizes, int n_in,
                              void* d_out, int out_size, void* d_ws, size_t ws_size,
                              hipStream_t stream) {
    (void)in_sizes; (void)n_in; (void)out_size; (void)ws_size;
    const float* x  = (const float*)d_in[0];
    const float* W1 = (const float*)d_in[1];
    const float* b1 = (const float*)d_in[2];
    const float* W2 = (const float*)d_in[3];
    const float* b2 = (const float*)d_in[4];
    const int*   ei = (const int*)d_in[5];
    float* out = (float*)d_out;

    char* ws = (char*)d_ws;
    int*      deg     = (int*)(ws + OFF_DEG);
    int*      gcount  = (int*)(ws + OFF_GC);
    int*      bbase   = (int*)(ws + OFF_BB);
    int*      bcursor = (int*)(ws + OFF_BC);
    float*    rs      = (float*)(ws + OFF_RS);
    int*      start   = (int*)(ws + OFF_START);
    int*      pairs   = (int*)(ws + OFF_PAIRS);
    _Float16* xh      = (_Float16*)(ws + OFF_XH);
    _Float16* W1f     = (_Float16*)(ws + OFF_W1F);
    _Float16* W2f     = (_Float16*)(ws + OFF_W2F);
    _Float16* agg     = (_Float16*)(ws + OFF_AGG);
    _Float16* hW      = (_Float16*)(ws + OFF_HW);
    short*    dds     = (short*)(ws + OFF_DDS);
    int*      gcount_s= (int*)(ws + OFF_GCS);
    int*      bbase_s = (int*)(ws + OFF_BBS);
    int*      bcursor_s=(int*)(ws + OFF_BCS);
    int*      chd     = (int*)(ws + OFF_CHD);
    int*      chs     = (int*)(ws + OFF_CHS);

    hipMemsetAsync(gcount, 0, 6144, stream);
    hipMemsetAsync(gcount_s, 0, 6144, stream);

    k_cvt_x<<<25000, 256, 0, stream>>>(x, xh);
    k_repack<<<288, 256, 0, stream>>>(W1, W2, W1f, W2f);
    k_bhist2<<<dim3(NCHUNK, 6), 256, 0, stream>>>(ei, gcount, gcount_s, chd, chs);
    k_bscan2<<<12, 256, 0, stream>>>(gcount, gcount_s, bbase, bcursor, bbase_s, bcursor_s);
    k_bpart<<<dim3(NCHUNK, 6), 256, 0, stream>>>(ei, chd, bcursor, pairs);
    k_bpart_s<<<dim3(NCHUNK, 6), 256, 0, stream>>>(ei, chs, bcursor_s, dds);
    k_bsort<<<dim3(NBUCK, 6), 256, 0, stream>>>(bbase, pairs, start, deg, rs);
    k_bcount_s<<<dim3(NBUCK, 6), 256, 0, stream>>>(bbase_s, dds, deg, rs);
    k_pull1<<<25000, 256, 0, stream>>>(pairs, start, deg, rs, xh, agg);
    k_gemm12<<<(MTILES + 3) / 4, 256, 0, stream>>>(agg, W1f, b1, W2f,
                                                   rs + 6 * (size_t)N_NODES, hW);
    k_pull2<<<25000, 256, 0, stream>>>(pairs + 3 * (size_t)N_EDGES,
                                       start + 3 * (size_t)N_NODES,
                                       deg + 6 * (size_t)N_NODES,
                                       rs + 6 * (size_t)N_NODES,
                                       hW, b2, out);
}